// Round 14
// baseline (197.037 us; speedup 1.0000x reference)
//
#include <hip/hip_runtime.h>
#include <hip/hip_bf16.h>
#include <stdint.h>

#define B_ 8
#define N_ 1024
#define C_ 1024
#define H_ 16

static constexpr float SCALE = 0.125f;            // 64^-0.5
static constexpr float LOG2E = 1.4426950408889634f;
static constexpr float SL    = SCALE * LOG2E;     // folded into Wq at cvt time

typedef __attribute__((ext_vector_type(4))) float f32x4;
typedef __attribute__((ext_vector_type(8))) short s16x8;

__device__ __forceinline__ ushort f2bf(float f) {
    union { float f; uint32_t u; } c; c.f = f;
    uint32_t u = c.u;
    return (ushort)((u + 0x7fffu + ((u >> 16) & 1u)) >> 16);
}

// compiler-friendly cast: hipcc fuses pairs into v_cvt_pk_bf16_f32 (m240)
__device__ __forceinline__ ushort f2bfc(float f) {
    union { __hip_bfloat16 h; ushort u; } c;
    c.h = __float2bfloat16(f);
    return c.u;
}

__device__ __forceinline__ void gload_lds16(const void* g, void* l) {
    __builtin_amdgcn_global_load_lds(
        (const __attribute__((address_space(1))) void*)g,
        (__attribute__((address_space(3))) void*)l,
        16, 0, 0);
}
__device__ __forceinline__ void gload_lds4(const void* g, void* l) {
    __builtin_amdgcn_global_load_lds(
        (const __attribute__((address_space(1))) void*)g,
        (__attribute__((address_space(3))) void*)l,
        4, 0, 0);
}

// ---------------- fused fp32 -> bf16 conversion for all three inputs ----------------
__global__ __launch_bounds__(256) void cvt_all(const float* __restrict__ x,
                                               const float* __restrict__ qkv_w,
                                               const float* __restrict__ proj_w,
                                               ushort* __restrict__ xb,
                                               ushort* __restrict__ wqkv,
                                               ushort* __restrict__ wproj) {
    int i = blockIdx.x * 256 + threadIdx.x;
    const float* src;
    ushort* dst;
    float sc = 1.0f;
    if (i < 2097152) {
        src = x; dst = xb;
    } else if (i < 2097152 + 786432) {
        i -= 2097152;
        src = qkv_w; dst = wqkv;
        if (i < 262144) sc = SL;
    } else {
        i -= 2097152 + 786432;
        src = proj_w; dst = wproj;
    }
    float4 v = ((const float4*)src)[i];
    ushort4 o = make_ushort4(f2bf(v.x * sc), f2bf(v.y * sc), f2bf(v.z * sc), f2bf(v.w * sc));
    ((ushort4*)dst)[i] = o;
}

// ---------------- 128x128 m97-structure GEMM: C = A * B^T (+T1 XCD swizzle) ----------------
template<int OUT_BF16>
__global__ __launch_bounds__(256) void gemm_bt(const ushort* __restrict__ A,
                                               const ushort* __restrict__ Bw,
                                               void* __restrict__ Cout,
                                               const float* __restrict__ bias,
                                               int M, int Nout, int K) {
    __shared__ ushort Asm[128 * 64];
    __shared__ ushort Bsm[128 * 64];
    const int t = threadIdx.x;
    const int l = t & 63, w = t >> 6;
    const int lq = l & 15, lg = l >> 4;

    int bid = blockIdx.y * gridDim.x + blockIdx.x;
    const int cpx = (gridDim.x * gridDim.y) >> 3;
    bid = (bid & 7) * cpx + (bid >> 3);
    const int trow = (bid / gridDim.x) * 128, tcol = (bid % gridDim.x) * 128;

    const int wrow = (w >> 1) * 64, wcol = (w & 1) * 64;

    f32x4 acc[4][4] = {};

    const int srow0 = t >> 3;
    const int sc8 = (((t & 7) ^ (srow0 & 7)) * 8);
    const size_t abase = (size_t)(trow + srow0) * K + sc8;
    const size_t bbase = (size_t)(tcol + srow0) * K + sc8;

    for (int k0 = 0; k0 < K; k0 += 64) {
#pragma unroll
        for (int i = 0; i < 4; ++i) {
            gload_lds16(A + abase + (size_t)i * 32 * K + k0, &Asm[(i * 256 + w * 64) * 8]);
            gload_lds16(Bw + bbase + (size_t)i * 32 * K + k0, &Bsm[(i * 256 + w * 64) * 8]);
        }
        __syncthreads();
#pragma unroll
        for (int kk = 0; kk < 2; ++kk) {
            s16x8 af[4], bf[4];
#pragma unroll
            for (int m = 0; m < 4; ++m) {
                int row = wrow + m * 16 + lq;
                int ch = (kk * 4 + lg) ^ (row & 7);
                af[m] = *(const s16x8*)&Asm[row * 64 + ch * 8];
            }
#pragma unroll
            for (int n = 0; n < 4; ++n) {
                int row = wcol + n * 16 + lq;
                int ch = (kk * 4 + lg) ^ (row & 7);
                bf[n] = *(const s16x8*)&Bsm[row * 64 + ch * 8];
            }
#pragma unroll
            for (int m = 0; m < 4; ++m)
#pragma unroll
                for (int n = 0; n < 4; ++n)
                    acc[m][n] = __builtin_amdgcn_mfma_f32_16x16x32_bf16(af[m], bf[n], acc[m][n], 0, 0, 0);
        }
        __syncthreads();
    }

#pragma unroll
    for (int m = 0; m < 4; ++m)
#pragma unroll
        for (int n = 0; n < 4; ++n)
#pragma unroll
            for (int r = 0; r < 4; ++r) {
                int row = trow + wrow + m * 16 + lg * 4 + r;
                int col = tcol + wcol + n * 16 + lq;
                if (OUT_BF16) {
                    ((ushort*)Cout)[(size_t)row * Nout + col] = f2bfc(acc[m][n][r]);
                } else {
                    ((float*)Cout)[(size_t)row * Nout + col] = acc[m][n][r] + bias[col];
                }
            }
}

// ---------------- 256x256 GEMM v4: TRIPLE-buffer BK=32 + counted vmcnt (true T4) ----------------
// r12/r13 nulls match m233's "2-phase ceiling" exactly: with double-buffering every staging
// DMA must land before the publish barrier -> forced vmcnt(0) drain. v4: 3 buffers of BK=32
// (96 KB LDS), stage tile kt+2 during kt; per-tile wait = vmcnt(4) -> waits only for loads
// issued a full tile earlier (free); the 4 newest DMAs stay in flight ACROSS the barrier
// (m201/m218: counted-vs-drain0 is THE lever). Swizzle for 4-chunk rows: chunk ^= (row>>1)&3
// -> 2-way on frag reads (free, m136); invariant under +128 rows (source swz same for j=0,1).
// Publish safety: each wave's vmcnt(4) BEFORE the barrier verifies its own buf[kt+1] DMAs
// landed; barrier then publishes to all waves (m201 pattern).
__global__ __launch_bounds__(512, 2) void gemm_bt256(const ushort* __restrict__ A,
                                                     const ushort* __restrict__ Bw,
                                                     ushort* __restrict__ Cout,
                                                     int M, int Nout, int K) {
    __shared__ ushort Asm[3][256 * 32];
    __shared__ ushort Bsm[3][256 * 32];
    const int t = threadIdx.x;
    const int l = t & 63, w = t >> 6;
    const int lq = l & 15, lg = l >> 4;
    const int wm = w >> 2, wn = w & 3;

    int bid = blockIdx.y * gridDim.x + blockIdx.x;
    const int cpx = (gridDim.x * gridDim.y) >> 3;
    bid = (bid & 7) * cpx + (bid >> 3);
    const int bx = bid % gridDim.x, by = bid / gridDim.x;
    const int trow = by * 256, tcol = bx * 256;

    f32x4 acc[8][4] = {};

    // staging: thread t covers chunks j*512+t (j=0,1); row = chunk>>2 (+j*128),
    // phys chunk t&3, source chunk pre-swizzled by (row>>1)&3
    const int srow = t >> 2;
    const int scc = ((t & 3) ^ ((srow >> 1) & 3)) * 8;
    const size_t abase = (size_t)(trow + srow) * K + scc;
    const size_t bbase = (size_t)(tcol + srow) * K + scc;

#define STAGE(buf, k0)                                                         \
    {                                                                          \
        _Pragma("unroll")                                                      \
        for (int j = 0; j < 2; ++j) {                                          \
            gload_lds16(A + abase + (size_t)j * 128 * K + (k0),                \
                        &Asm[buf][(j * 512 + t) * 8]);                         \
            gload_lds16(Bw + bbase + (size_t)j * 128 * K + (k0),               \
                        &Bsm[buf][(j * 512 + t) * 8]);                         \
        }                                                                      \
    }

    STAGE(0, 0);
    STAGE(1, 32);
    asm volatile("s_waitcnt vmcnt(4)" ::: "memory");   // tile 0 landed; tile 1 in flight
    __builtin_amdgcn_s_barrier();

    const int NT = K / 32;
    for (int kt = 0; kt < NT; ++kt) {
        const int cur = kt % 3;
        if (kt + 2 < NT) STAGE((kt + 2) % 3, (kt + 2) * 32);

        s16x8 af[8], bf[4];
#pragma unroll
        for (int m = 0; m < 8; ++m) {
            const int row = wm * 128 + m * 16 + lq;
            af[m] = *(const s16x8*)&Asm[cur][row * 32 + ((lg ^ ((row >> 1) & 3)) * 8)];
        }
#pragma unroll
        for (int n = 0; n < 4; ++n) {
            const int row = wn * 64 + n * 16 + lq;
            bf[n] = *(const s16x8*)&Bsm[cur][row * 32 + ((lg ^ ((row >> 1) & 3)) * 8)];
        }

        __builtin_amdgcn_s_setprio(1);
#pragma unroll
        for (int m = 0; m < 8; ++m)
#pragma unroll
            for (int n = 0; n < 4; ++n)
                acc[m][n] = __builtin_amdgcn_mfma_f32_16x16x32_bf16(af[m], bf[n], acc[m][n], 0, 0, 0);
        __builtin_amdgcn_s_setprio(0);

        // counted wait: buf[kt+1]'s DMAs (issued during kt-1) must be landed; the 4 newest
        // (for kt+2, issued this tile) stay in flight across the barrier.
        if (kt + 2 < NT) asm volatile("s_waitcnt vmcnt(4)" ::: "memory");
        else             asm volatile("s_waitcnt vmcnt(0)" ::: "memory");
        __builtin_amdgcn_s_barrier();
    }

#pragma unroll
    for (int mt = 0; mt < 8; ++mt)
#pragma unroll
        for (int nt = 0; nt < 4; ++nt)
#pragma unroll
            for (int r = 0; r < 4; ++r) {
                int row = trow + wm * 128 + mt * 16 + lg * 4 + r;
                int col = tcol + wn * 64 + nt * 16 + lq;
                Cout[(size_t)row * Nout + col] = f2bfc(acc[mt][nt][r]);
            }
#undef STAGE
}

// ---------------- fused flash attention: QBLK=256, KVBLK=128-staging / 2x64-compute ----------
// Staging indices from r10 (correctness-validated there; r10's regression was VGPR spill from
// 8-group score arrays, not indexing). Compute = two sequential 64-key passes with r13's
// reg-light per-pass profile -> barriers & loop overhead halved at unchanged VGPR.
__global__ __launch_bounds__(512, 4) void attn_fwd(const ushort* __restrict__ qk,
                                                   const ushort* __restrict__ vt,
                                                   ushort* __restrict__ attn_out) {
    __shared__ ushort Klds[128 * 64];
    __shared__ ushort Vlds[64 * 128];

    const int t = threadIdx.x, l = t & 63, w = t >> 6;
    const int lq = l & 15, lg = l >> 4;

    const int serial = blockIdx.x + 4 * blockIdx.y;
    const int logical = (serial & 7) * 64 + (serial >> 3);
    const int qt = logical & 3;
    const int bh = logical >> 2;
    const int b = bh >> 4, h = bh & 15;

    const int qbase = qt * 256 + w * 32 + lq;
    const size_t qoff0 = (size_t)(b * N_ + qbase) * 2048 + h * 64;
    const size_t qoff1 = qoff0 + (size_t)16 * 2048;
    const s16x8 qa0 = *(const s16x8*)&qk[qoff0 + lg * 8];
    const s16x8 qa1 = *(const s16x8*)&qk[qoff0 + 32 + lg * 8];
    const s16x8 qb0 = *(const s16x8*)&qk[qoff1 + lg * 8];
    const s16x8 qb1 = *(const s16x8*)&qk[qoff1 + 32 + lg * 8];

    float lr0 = 0.f, lr1 = 0.f;
    f32x4 o0[4] = {}, o1[4] = {};

    // K staging: thread t -> rows t>>3 and 64+(t>>3); chunk t&7 pre-swizzled (r10)
    const int srow0 = t >> 3;
    const int sc8 = ((t & 7) ^ (srow0 & 7)) * 8;
    const size_t kgbase = (size_t)(b * N_ + srow0) * 2048 + 1024 + h * 64 + sc8;

    // V staging: 8 gload_lds4/thread; DMA j covers d-row w*8+j of Vlds[64][128] (r10)
    const ushort* vptr[8];
#pragma unroll
    for (int j = 0; j < 8; ++j) {
        const int d = w * 8 + j;
        const int c = (l >> 2) ^ (d & 7);
        const int s = c * 8 + (l & 3) * 2;
        const int key = (2 * (s >> 5) + ((s >> 2) & 1)) * 16 + ((s >> 3) & 3) * 4 + (s & 3);
        vptr[j] = vt + (size_t)(h * 64 + d) * (B_ * N_) + b * N_ + key;
    }

    for (int kt = 0; kt < N_ / 128; ++kt) {
        const size_t koff = kgbase + (size_t)kt * 128 * 2048;
        gload_lds16(qk + koff, &Klds[w * 512]);
        gload_lds16(qk + koff + (size_t)64 * 2048, &Klds[4096 + w * 512]);
#pragma unroll
        for (int j = 0; j < 8; ++j)
            gload_lds4(vptr[j] + kt * 128, &Vlds[(w * 8 + j) * 128]);
        __syncthreads();

#pragma unroll
        for (int p = 0; p < 2; ++p) {
            f32x4 s0[4], s1[4];
#pragma unroll
            for (int g = 0; g < 4; ++g) {
                int key = p * 64 + g * 16 + lq;
                const s16x8 kf0 = *(const s16x8*)&Klds[key * 64 + ((lg ^ (key & 7)) * 8)];
                const s16x8 kf1 = *(const s16x8*)&Klds[key * 64 + (((4 + lg) ^ (key & 7)) * 8)];
                f32x4 z0 = {}, z1 = {};
                z0    = __builtin_amdgcn_mfma_f32_16x16x32_bf16(kf0, qa0, z0, 0, 0, 0);
                s0[g] = __builtin_amdgcn_mfma_f32_16x16x32_bf16(kf1, qa1, z0, 0, 0, 0);
                z1    = __builtin_amdgcn_mfma_f32_16x16x32_bf16(kf0, qb0, z1, 0, 0, 0);
                s1[g] = __builtin_amdgcn_mfma_f32_16x16x32_bf16(kf1, qb1, z1, 0, 0, 0);
            }

#pragma unroll
            for (int kb = 0; kb < 2; ++kb) {
                s16x8 pf0, pf1;
#pragma unroll
                for (int i = 0; i < 4; ++i) {
                    float a0 = __builtin_amdgcn_exp2f(s0[2 * kb][i]);
                    float a1 = __builtin_amdgcn_exp2f(s0[2 * kb + 1][i]);
                    float b0 = __builtin_amdgcn_exp2f(s1[2 * kb][i]);
                    float b1 = __builtin_amdgcn_exp2f(s1[2 * kb + 1][i]);
                    lr0 += a0 + a1;
                    lr1 += b0 + b1;
                    pf0[i] = (short)f2bfc(a0); pf0[4 + i] = (short)f2bfc(a1);
                    pf1[i] = (short)f2bfc(b0); pf1[4 + i] = (short)f2bfc(b1);
                }
#pragma unroll
                for (int ds = 0; ds < 4; ++ds) {
                    const s16x8 vf = *(const s16x8*)
                        &Vlds[(ds * 16 + lq) * 128 + (((p * 8 + kb * 4 + lg) ^ (lq & 7)) * 8)];
                    o0[ds] = __builtin_amdgcn_mfma_f32_16x16x32_bf16(pf0, vf, o0[ds], 0, 0, 0);
                    o1[ds] = __builtin_amdgcn_mfma_f32_16x16x32_bf16(pf1, vf, o1[ds], 0, 0, 0);
                }
            }
        }
        __syncthreads();
    }

    lr0 += __shfl_xor(lr0, 16); lr0 += __shfl_xor(lr0, 32);
    lr1 += __shfl_xor(lr1, 16); lr1 += __shfl_xor(lr1, 32);

#pragma unroll
    for (int r = 0; r < 4; ++r) {
        float rl0 = 1.f / __shfl(lr0, lg * 4 + r);
        float rl1 = 1.f / __shfl(lr1, lg * 4 + r);
        int orow = qt * 256 + w * 32 + lg * 4 + r;
        size_t base0 = (size_t)(b * N_ + orow) * C_ + h * 64 + lq;
        size_t base1 = base0 + (size_t)16 * C_;
#pragma unroll
        for (int ds = 0; ds < 4; ++ds) {
            attn_out[base0 + ds * 16] = f2bfc(o0[ds][r] * rl0);
            attn_out[base1 + ds * 16] = f2bfc(o1[ds][r] * rl1);
        }
    }
}

extern "C" void kernel_launch(void* const* d_in, const int* in_sizes, int n_in,
                              void* d_out, int out_size, void* d_ws, size_t ws_size,
                              hipStream_t stream) {
    const float* x      = (const float*)d_in[0];
    const float* qkv_w  = (const float*)d_in[1];
    const float* proj_w = (const float*)d_in[2];
    const float* proj_b = (const float*)d_in[3];
    float* out = (float*)d_out;

    ushort* ws    = (ushort*)d_ws;
    ushort* xb    = ws;                                   //  8192*1024
    ushort* wqkv  = xb + (size_t)8192 * 1024;             //  3072*1024
    ushort* wproj = wqkv + (size_t)3072 * 1024;           //  1024*1024
    ushort* qkb   = wproj + (size_t)1024 * 1024;          //  8192*2048
    ushort* vtb   = qkb + (size_t)8192 * 2048;            //  1024*8192
    ushort* attn  = vtb + (size_t)1024 * 8192;            //  8192*1024

    cvt_all<<<12288, 256, 0, stream>>>(x, qkv_w, proj_w, xb, wqkv, wproj);

    // Q,K: [token][2048] via 256^2 v4 (triple-buffer BK=32, counted vmcnt)
    gemm_bt256<<<dim3(8, 32), 512, 0, stream>>>(xb, wqkv, qkb, 8192, 2048, 1024);
    // V^T: [c][token]
    gemm_bt<1><<<dim3(64, 8), 256, 0, stream>>>(wqkv + (size_t)2048 * 1024, xb, (void*)vtb,
                                                nullptr, 1024, 8192, 1024);

    attn_fwd<<<dim3(4, 128), 512, 0, stream>>>(qkb, vtb, attn);

    gemm_bt<0><<<dim3(8, 64), 256, 0, stream>>>(attn, wproj, (void*)out, proj_b, 8192, 1024, 1024);
}

// Round 15
// 152.101 us; speedup vs baseline: 1.2954x; 1.2954x over previous
//
#include <hip/hip_runtime.h>
#include <hip/hip_bf16.h>
#include <stdint.h>

#define B_ 8
#define N_ 1024
#define C_ 1024
#define H_ 16

static constexpr float SCALE = 0.125f;            // 64^-0.5
static constexpr float LOG2E = 1.4426950408889634f;
static constexpr float SL    = SCALE * LOG2E;     // folded into Wq at cvt time

typedef __attribute__((ext_vector_type(4))) float f32x4;
typedef __attribute__((ext_vector_type(8))) short s16x8;

__device__ __forceinline__ ushort f2bf(float f) {
    union { float f; uint32_t u; } c; c.f = f;
    uint32_t u = c.u;
    return (ushort)((u + 0x7fffu + ((u >> 16) & 1u)) >> 16);
}

// compiler-friendly cast: hipcc fuses pairs into v_cvt_pk_bf16_f32 (m240)
__device__ __forceinline__ ushort f2bfc(float f) {
    union { __hip_bfloat16 h; ushort u; } c;
    c.h = __float2bfloat16(f);
    return c.u;
}

__device__ __forceinline__ void gload_lds16(const void* g, void* l) {
    __builtin_amdgcn_global_load_lds(
        (const __attribute__((address_space(1))) void*)g,
        (__attribute__((address_space(3))) void*)l,
        16, 0, 0);
}
__device__ __forceinline__ void gload_lds4(const void* g, void* l) {
    __builtin_amdgcn_global_load_lds(
        (const __attribute__((address_space(1))) void*)g,
        (__attribute__((address_space(3))) void*)l,
        4, 0, 0);
}

// ---------------- fused fp32 -> bf16 conversion for all three inputs ----------------
__global__ __launch_bounds__(256) void cvt_all(const float* __restrict__ x,
                                               const float* __restrict__ qkv_w,
                                               const float* __restrict__ proj_w,
                                               ushort* __restrict__ xb,
                                               ushort* __restrict__ wqkv,
                                               ushort* __restrict__ wproj) {
    int i = blockIdx.x * 256 + threadIdx.x;
    const float* src;
    ushort* dst;
    float sc = 1.0f;
    if (i < 2097152) {
        src = x; dst = xb;
    } else if (i < 2097152 + 786432) {
        i -= 2097152;
        src = qkv_w; dst = wqkv;
        if (i < 262144) sc = SL;
    } else {
        i -= 2097152 + 786432;
        src = proj_w; dst = wproj;
    }
    float4 v = ((const float4*)src)[i];
    ushort4 o = make_ushort4(f2bf(v.x * sc), f2bf(v.y * sc), f2bf(v.z * sc), f2bf(v.w * sc));
    ((ushort4*)dst)[i] = o;
}

// ---------------- 128x128 m97-structure GEMM: C = A * B^T (+T1 XCD swizzle) ----------------
template<int OUT_BF16>
__global__ __launch_bounds__(256) void gemm_bt(const ushort* __restrict__ A,
                                               const ushort* __restrict__ Bw,
                                               void* __restrict__ Cout,
                                               const float* __restrict__ bias,
                                               int M, int Nout, int K) {
    __shared__ ushort Asm[128 * 64];
    __shared__ ushort Bsm[128 * 64];
    const int t = threadIdx.x;
    const int l = t & 63, w = t >> 6;
    const int lq = l & 15, lg = l >> 4;

    int bid = blockIdx.y * gridDim.x + blockIdx.x;
    const int cpx = (gridDim.x * gridDim.y) >> 3;
    bid = (bid & 7) * cpx + (bid >> 3);
    const int trow = (bid / gridDim.x) * 128, tcol = (bid % gridDim.x) * 128;

    const int wrow = (w >> 1) * 64, wcol = (w & 1) * 64;

    f32x4 acc[4][4] = {};

    const int srow0 = t >> 3;
    const int sc8 = (((t & 7) ^ (srow0 & 7)) * 8);
    const size_t abase = (size_t)(trow + srow0) * K + sc8;
    const size_t bbase = (size_t)(tcol + srow0) * K + sc8;

    for (int k0 = 0; k0 < K; k0 += 64) {
#pragma unroll
        for (int i = 0; i < 4; ++i) {
            gload_lds16(A + abase + (size_t)i * 32 * K + k0, &Asm[(i * 256 + w * 64) * 8]);
            gload_lds16(Bw + bbase + (size_t)i * 32 * K + k0, &Bsm[(i * 256 + w * 64) * 8]);
        }
        __syncthreads();
#pragma unroll
        for (int kk = 0; kk < 2; ++kk) {
            s16x8 af[4], bf[4];
#pragma unroll
            for (int m = 0; m < 4; ++m) {
                int row = wrow + m * 16 + lq;
                int ch = (kk * 4 + lg) ^ (row & 7);
                af[m] = *(const s16x8*)&Asm[row * 64 + ch * 8];
            }
#pragma unroll
            for (int n = 0; n < 4; ++n) {
                int row = wcol + n * 16 + lq;
                int ch = (kk * 4 + lg) ^ (row & 7);
                bf[n] = *(const s16x8*)&Bsm[row * 64 + ch * 8];
            }
#pragma unroll
            for (int m = 0; m < 4; ++m)
#pragma unroll
                for (int n = 0; n < 4; ++n)
                    acc[m][n] = __builtin_amdgcn_mfma_f32_16x16x32_bf16(af[m], bf[n], acc[m][n], 0, 0, 0);
        }
        __syncthreads();
    }

#pragma unroll
    for (int m = 0; m < 4; ++m)
#pragma unroll
        for (int n = 0; n < 4; ++n)
#pragma unroll
            for (int r = 0; r < 4; ++r) {
                int row = trow + wrow + m * 16 + lg * 4 + r;
                int col = tcol + wcol + n * 16 + lq;
                if (OUT_BF16) {
                    ((ushort*)Cout)[(size_t)row * Nout + col] = f2bfc(acc[m][n][r]);
                } else {
                    ((float*)Cout)[(size_t)row * Nout + col] = acc[m][n][r] + bias[col];
                }
            }
}

// ---------------- 256x256 GEMM v4: TRIPLE-buffer BK=32 + counted vmcnt (true T4) ----------------
// 3 buffers of BK=32 (96 KB LDS), stage tile kt+2 during kt; per-tile wait = vmcnt(4) ->
// waits only for loads issued a full tile earlier; the 4 newest DMAs stay in flight ACROSS
// the barrier (m218: counted-vs-drain0 is THE lever). Swizzle: chunk ^= (row>>1)&3.
__global__ __launch_bounds__(512, 2) void gemm_bt256(const ushort* __restrict__ A,
                                                     const ushort* __restrict__ Bw,
                                                     ushort* __restrict__ Cout,
                                                     int M, int Nout, int K) {
    __shared__ ushort Asm[3][256 * 32];
    __shared__ ushort Bsm[3][256 * 32];
    const int t = threadIdx.x;
    const int l = t & 63, w = t >> 6;
    const int lq = l & 15, lg = l >> 4;
    const int wm = w >> 2, wn = w & 3;

    int bid = blockIdx.y * gridDim.x + blockIdx.x;
    const int cpx = (gridDim.x * gridDim.y) >> 3;
    bid = (bid & 7) * cpx + (bid >> 3);
    const int bx = bid % gridDim.x, by = bid / gridDim.x;
    const int trow = by * 256, tcol = bx * 256;

    f32x4 acc[8][4] = {};

    const int srow = t >> 2;
    const int scc = ((t & 3) ^ ((srow >> 1) & 3)) * 8;
    const size_t abase = (size_t)(trow + srow) * K + scc;
    const size_t bbase = (size_t)(tcol + srow) * K + scc;

#define STAGE(buf, k0)                                                         \
    {                                                                          \
        _Pragma("unroll")                                                      \
        for (int j = 0; j < 2; ++j) {                                          \
            gload_lds16(A + abase + (size_t)j * 128 * K + (k0),                \
                        &Asm[buf][(j * 512 + t) * 8]);                         \
            gload_lds16(Bw + bbase + (size_t)j * 128 * K + (k0),               \
                        &Bsm[buf][(j * 512 + t) * 8]);                         \
        }                                                                      \
    }

    STAGE(0, 0);
    STAGE(1, 32);
    asm volatile("s_waitcnt vmcnt(4)" ::: "memory");   // tile 0 landed; tile 1 in flight
    __builtin_amdgcn_s_barrier();

    const int NT = K / 32;
    for (int kt = 0; kt < NT; ++kt) {
        const int cur = kt % 3;
        if (kt + 2 < NT) STAGE((kt + 2) % 3, (kt + 2) * 32);

        s16x8 af[8], bf[4];
#pragma unroll
        for (int m = 0; m < 8; ++m) {
            const int row = wm * 128 + m * 16 + lq;
            af[m] = *(const s16x8*)&Asm[cur][row * 32 + ((lg ^ ((row >> 1) & 3)) * 8)];
        }
#pragma unroll
        for (int n = 0; n < 4; ++n) {
            const int row = wn * 64 + n * 16 + lq;
            bf[n] = *(const s16x8*)&Bsm[cur][row * 32 + ((lg ^ ((row >> 1) & 3)) * 8)];
        }

        __builtin_amdgcn_s_setprio(1);
#pragma unroll
        for (int m = 0; m < 8; ++m)
#pragma unroll
            for (int n = 0; n < 4; ++n)
                acc[m][n] = __builtin_amdgcn_mfma_f32_16x16x32_bf16(af[m], bf[n], acc[m][n], 0, 0, 0);
        __builtin_amdgcn_s_setprio(0);

        if (kt + 2 < NT) asm volatile("s_waitcnt vmcnt(4)" ::: "memory");
        else             asm volatile("s_waitcnt vmcnt(0)" ::: "memory");
        __builtin_amdgcn_s_barrier();
    }

#pragma unroll
    for (int mt = 0; mt < 8; ++mt)
#pragma unroll
        for (int nt = 0; nt < 4; ++nt)
#pragma unroll
            for (int r = 0; r < 4; ++r) {
                int row = trow + wm * 128 + mt * 16 + lg * 4 + r;
                int col = tcol + wn * 64 + nt * 16 + lq;
                Cout[(size_t)row * Nout + col] = f2bfc(acc[mt][nt][r]);
            }
#undef STAGE
}

// ---------------- fused flash attention (QBLK=256, KVBLK=64 -- r13 exact) ----------------
// KVBLK=128 is permanently rejected: twice measured (r10, r14) at ~96us with 159MB FETCH
// (zero L2 reuse), vs KVBLK=64's ~37us / ~25MB.
__global__ __launch_bounds__(512, 4) void attn_fwd(const ushort* __restrict__ qk,
                                                   const ushort* __restrict__ vt,
                                                   ushort* __restrict__ attn_out) {
    __shared__ ushort Klds[64 * 64];
    __shared__ ushort Vlds[64 * 64];

    const int t = threadIdx.x, l = t & 63, w = t >> 6;
    const int lq = l & 15, lg = l >> 4;

    const int serial = blockIdx.x + 4 * blockIdx.y;
    const int logical = (serial & 7) * 64 + (serial >> 3);
    const int qt = logical & 3;
    const int bh = logical >> 2;
    const int b = bh >> 4, h = bh & 15;

    const int qbase = qt * 256 + w * 32 + lq;
    const size_t qoff0 = (size_t)(b * N_ + qbase) * 2048 + h * 64;
    const size_t qoff1 = qoff0 + (size_t)16 * 2048;
    const s16x8 qa0 = *(const s16x8*)&qk[qoff0 + lg * 8];
    const s16x8 qa1 = *(const s16x8*)&qk[qoff0 + 32 + lg * 8];
    const s16x8 qb0 = *(const s16x8*)&qk[qoff1 + lg * 8];
    const s16x8 qb1 = *(const s16x8*)&qk[qoff1 + 32 + lg * 8];

    float lr0 = 0.f, lr1 = 0.f;
    f32x4 o0[4] = {}, o1[4] = {};

    const int srow0 = t >> 3;
    const int sc8 = ((t & 7) ^ (srow0 & 7)) * 8;
    const size_t kgbase = (size_t)(b * N_ + srow0) * 2048 + 1024 + h * 64 + sc8;

    const ushort* vptr[4];
#pragma unroll
    for (int j = 0; j < 4; ++j) {
        const int d = 8 * w + 2 * j + (l >> 5);
        const int c = ((l & 31) >> 2) ^ (d & 7);
        const int s = c * 8 + (l & 3) * 2;
        const int key = (s >> 5) * 32 + ((s >> 2) & 1) * 16 + ((s >> 3) & 3) * 4 + (s & 3);
        vptr[j] = vt + (size_t)(h * 64 + d) * (B_ * N_) + b * N_ + key;
    }

    for (int kt = 0; kt < N_ / 64; ++kt) {
        gload_lds16(qk + kgbase + (size_t)kt * 64 * 2048, &Klds[w * 512]);
#pragma unroll
        for (int j = 0; j < 4; ++j)
            gload_lds4(vptr[j] + kt * 64, &Vlds[w * 512 + j * 128]);
        __syncthreads();

        f32x4 s0[4], s1[4];
#pragma unroll
        for (int g = 0; g < 4; ++g) {
            int key = g * 16 + lq;
            const s16x8 kf0 = *(const s16x8*)&Klds[key * 64 + ((lg ^ (key & 7)) * 8)];
            const s16x8 kf1 = *(const s16x8*)&Klds[key * 64 + (((4 + lg) ^ (key & 7)) * 8)];
            f32x4 z0 = {}, z1 = {};
            z0    = __builtin_amdgcn_mfma_f32_16x16x32_bf16(kf0, qa0, z0, 0, 0, 0);
            s0[g] = __builtin_amdgcn_mfma_f32_16x16x32_bf16(kf1, qa1, z0, 0, 0, 0);
            z1    = __builtin_amdgcn_mfma_f32_16x16x32_bf16(kf0, qb0, z1, 0, 0, 0);
            s1[g] = __builtin_amdgcn_mfma_f32_16x16x32_bf16(kf1, qb1, z1, 0, 0, 0);
        }

#pragma unroll
        for (int kb = 0; kb < 2; ++kb) {
            s16x8 pf0, pf1;
#pragma unroll
            for (int i = 0; i < 4; ++i) {
                float a0 = __builtin_amdgcn_exp2f(s0[2 * kb][i]);
                float a1 = __builtin_amdgcn_exp2f(s0[2 * kb + 1][i]);
                float b0 = __builtin_amdgcn_exp2f(s1[2 * kb][i]);
                float b1 = __builtin_amdgcn_exp2f(s1[2 * kb + 1][i]);
                lr0 += a0 + a1;
                lr1 += b0 + b1;
                pf0[i] = (short)f2bfc(a0); pf0[4 + i] = (short)f2bfc(a1);
                pf1[i] = (short)f2bfc(b0); pf1[4 + i] = (short)f2bfc(b1);
            }
#pragma unroll
            for (int ds = 0; ds < 4; ++ds) {
                const s16x8 vf = *(const s16x8*)
                    &Vlds[(ds * 16 + lq) * 64 + (((kb * 4 + lg) ^ (lq & 7)) * 8)];
                o0[ds] = __builtin_amdgcn_mfma_f32_16x16x32_bf16(pf0, vf, o0[ds], 0, 0, 0);
                o1[ds] = __builtin_amdgcn_mfma_f32_16x16x32_bf16(pf1, vf, o1[ds], 0, 0, 0);
            }
        }
        __syncthreads();
    }

    lr0 += __shfl_xor(lr0, 16); lr0 += __shfl_xor(lr0, 32);
    lr1 += __shfl_xor(lr1, 16); lr1 += __shfl_xor(lr1, 32);

#pragma unroll
    for (int r = 0; r < 4; ++r) {
        float rl0 = 1.f / __shfl(lr0, lg * 4 + r);
        float rl1 = 1.f / __shfl(lr1, lg * 4 + r);
        int orow = qt * 256 + w * 32 + lg * 4 + r;
        size_t base0 = (size_t)(b * N_ + orow) * C_ + h * 64 + lq;
        size_t base1 = base0 + (size_t)16 * C_;
#pragma unroll
        for (int ds = 0; ds < 4; ++ds) {
            attn_out[base0 + ds * 16] = f2bfc(o0[ds][r] * rl0);
            attn_out[base1 + ds * 16] = f2bfc(o1[ds][r] * rl1);
        }
    }
}

extern "C" void kernel_launch(void* const* d_in, const int* in_sizes, int n_in,
                              void* d_out, int out_size, void* d_ws, size_t ws_size,
                              hipStream_t stream) {
    const float* x      = (const float*)d_in[0];
    const float* qkv_w  = (const float*)d_in[1];
    const float* proj_w = (const float*)d_in[2];
    const float* proj_b = (const float*)d_in[3];
    float* out = (float*)d_out;

    ushort* ws    = (ushort*)d_ws;
    ushort* xb    = ws;                                   //  8192*1024
    ushort* wqkv  = xb + (size_t)8192 * 1024;             //  3072*1024
    ushort* wproj = wqkv + (size_t)3072 * 1024;           //  1024*1024
    ushort* qkb   = wproj + (size_t)1024 * 1024;          //  8192*2048
    ushort* vtb   = qkb + (size_t)8192 * 2048;            //  1024*8192
    ushort* attn  = vtb + (size_t)1024 * 8192;            //  8192*1024

    cvt_all<<<12288, 256, 0, stream>>>(x, qkv_w, proj_w, xb, wqkv, wproj);

    // Q,K: [token][2048] via 256^2 v4 (triple-buffer BK=32, counted vmcnt)
    gemm_bt256<<<dim3(8, 32), 512, 0, stream>>>(xb, wqkv, qkb, 8192, 2048, 1024);
    // V^T: [c][token]
    gemm_bt<1><<<dim3(64, 8), 256, 0, stream>>>(wqkv + (size_t)2048 * 1024, xb, (void*)vtb,
                                                nullptr, 1024, 8192, 1024);

    attn_fwd<<<dim3(4, 128), 512, 0, stream>>>(qkb, vtb, attn);

    gemm_bt<0><<<dim3(8, 64), 256, 0, stream>>>(attn, wproj, (void*)out, proj_b, 8192, 1024, 1024);
}

// Round 16
// 142.914 us; speedup vs baseline: 1.3787x; 1.0643x over previous
//
#include <hip/hip_runtime.h>
#include <hip/hip_bf16.h>
#include <stdint.h>

#define B_ 8
#define N_ 1024
#define C_ 1024
#define H_ 16

static constexpr float SCALE = 0.125f;            // 64^-0.5
static constexpr float LOG2E = 1.4426950408889634f;
static constexpr float SL    = SCALE * LOG2E;     // folded into Wq at cvt time

typedef __attribute__((ext_vector_type(4))) float f32x4;
typedef __attribute__((ext_vector_type(8))) short s16x8;

__device__ __forceinline__ ushort f2bf(float f) {
    union { float f; uint32_t u; } c; c.f = f;
    uint32_t u = c.u;
    return (ushort)((u + 0x7fffu + ((u >> 16) & 1u)) >> 16);
}

// compiler-friendly cast: hipcc fuses pairs into v_cvt_pk_bf16_f32 (m240)
__device__ __forceinline__ ushort f2bfc(float f) {
    union { __hip_bfloat16 h; ushort u; } c;
    c.h = __float2bfloat16(f);
    return c.u;
}

__device__ __forceinline__ void gload_lds16(const void* g, void* l) {
    __builtin_amdgcn_global_load_lds(
        (const __attribute__((address_space(1))) void*)g,
        (__attribute__((address_space(3))) void*)l,
        16, 0, 0);
}
__device__ __forceinline__ void gload_lds4(const void* g, void* l) {
    __builtin_amdgcn_global_load_lds(
        (const __attribute__((address_space(1))) void*)g,
        (__attribute__((address_space(3))) void*)l,
        4, 0, 0);
}

// ---------------- fused fp32 -> bf16 conversion for all three inputs ----------------
__global__ __launch_bounds__(256) void cvt_all(const float* __restrict__ x,
                                               const float* __restrict__ qkv_w,
                                               const float* __restrict__ proj_w,
                                               ushort* __restrict__ xb,
                                               ushort* __restrict__ wqkv,
                                               ushort* __restrict__ wproj) {
    int i = blockIdx.x * 256 + threadIdx.x;
    const float* src;
    ushort* dst;
    float sc = 1.0f;
    if (i < 2097152) {
        src = x; dst = xb;
    } else if (i < 2097152 + 786432) {
        i -= 2097152;
        src = qkv_w; dst = wqkv;
        if (i < 262144) sc = SL;
    } else {
        i -= 2097152 + 786432;
        src = proj_w; dst = wproj;
    }
    float4 v = ((const float4*)src)[i];
    ushort4 o = make_ushort4(f2bf(v.x * sc), f2bf(v.y * sc), f2bf(v.z * sc), f2bf(v.w * sc));
    ((ushort4*)dst)[i] = o;
}

// ---------------- 128x128 m97-structure GEMM: C = A * B^T (+T1 XCD swizzle) ----------------
template<int OUT_BF16>
__global__ __launch_bounds__(256) void gemm_bt(const ushort* __restrict__ A,
                                               const ushort* __restrict__ Bw,
                                               void* __restrict__ Cout,
                                               const float* __restrict__ bias,
                                               int M, int Nout, int K) {
    __shared__ ushort Asm[128 * 64];
    __shared__ ushort Bsm[128 * 64];
    const int t = threadIdx.x;
    const int l = t & 63, w = t >> 6;
    const int lq = l & 15, lg = l >> 4;

    int bid = blockIdx.y * gridDim.x + blockIdx.x;
    const int cpx = (gridDim.x * gridDim.y) >> 3;
    bid = (bid & 7) * cpx + (bid >> 3);
    const int trow = (bid / gridDim.x) * 128, tcol = (bid % gridDim.x) * 128;

    const int wrow = (w >> 1) * 64, wcol = (w & 1) * 64;

    f32x4 acc[4][4] = {};

    const int srow0 = t >> 3;
    const int sc8 = (((t & 7) ^ (srow0 & 7)) * 8);
    const size_t abase = (size_t)(trow + srow0) * K + sc8;
    const size_t bbase = (size_t)(tcol + srow0) * K + sc8;

    for (int k0 = 0; k0 < K; k0 += 64) {
#pragma unroll
        for (int i = 0; i < 4; ++i) {
            gload_lds16(A + abase + (size_t)i * 32 * K + k0, &Asm[(i * 256 + w * 64) * 8]);
            gload_lds16(Bw + bbase + (size_t)i * 32 * K + k0, &Bsm[(i * 256 + w * 64) * 8]);
        }
        __syncthreads();
#pragma unroll
        for (int kk = 0; kk < 2; ++kk) {
            s16x8 af[4], bf[4];
#pragma unroll
            for (int m = 0; m < 4; ++m) {
                int row = wrow + m * 16 + lq;
                int ch = (kk * 4 + lg) ^ (row & 7);
                af[m] = *(const s16x8*)&Asm[row * 64 + ch * 8];
            }
#pragma unroll
            for (int n = 0; n < 4; ++n) {
                int row = wcol + n * 16 + lq;
                int ch = (kk * 4 + lg) ^ (row & 7);
                bf[n] = *(const s16x8*)&Bsm[row * 64 + ch * 8];
            }
#pragma unroll
            for (int m = 0; m < 4; ++m)
#pragma unroll
                for (int n = 0; n < 4; ++n)
                    acc[m][n] = __builtin_amdgcn_mfma_f32_16x16x32_bf16(af[m], bf[n], acc[m][n], 0, 0, 0);
        }
        __syncthreads();
    }

#pragma unroll
    for (int m = 0; m < 4; ++m)
#pragma unroll
        for (int n = 0; n < 4; ++n)
#pragma unroll
            for (int r = 0; r < 4; ++r) {
                int row = trow + wrow + m * 16 + lg * 4 + r;
                int col = tcol + wcol + n * 16 + lq;
                if (OUT_BF16) {
                    ((ushort*)Cout)[(size_t)row * Nout + col] = f2bfc(acc[m][n][r]);
                } else {
                    ((float*)Cout)[(size_t)row * Nout + col] = acc[m][n][r] + bias[col];
                }
            }
}

// ---------------- 256x256 dbuf GEMM v3 (best measured of 4 schedule variants) ----------------
// Schedule ledger at this shape (M8192 N2048 K1024): v1 10-barrier=50.3us, v2 1-barrier=50.5,
// v3 pipelined-frags=50.4, v4 triple-buf counted-vmcnt=55.3 -> all at the documented 2-phase
// ceiling (m248: 2ph=655-666 TF @256^2 K=1024). The m201 8-phase schedule (+~25%) could not be
// reproduced from spec (2 attempts + 1 failed race-audit reconstruction); v3 retained.
// setprio REMOVED per m190: on barrier-lockstep GEMM it measured -1.5%.
__global__ __launch_bounds__(512, 2) void gemm_bt256(const ushort* __restrict__ A,
                                                     const ushort* __restrict__ Bw,
                                                     ushort* __restrict__ Cout,
                                                     int M, int Nout, int K) {
    __shared__ ushort Asm[2][256 * 64];
    __shared__ ushort Bsm[2][256 * 64];
    const int t = threadIdx.x;
    const int l = t & 63, w = t >> 6;
    const int lq = l & 15, lg = l >> 4;
    const int wm = w >> 2, wn = w & 3;

    int bid = blockIdx.y * gridDim.x + blockIdx.x;
    const int cpx = (gridDim.x * gridDim.y) >> 3;
    bid = (bid & 7) * cpx + (bid >> 3);
    const int bx = bid % gridDim.x, by = bid / gridDim.x;
    const int trow = by * 256, tcol = bx * 256;

    f32x4 acc[8][4] = {};

    const int srow = t >> 3;
    const int scc = ((t & 7) ^ (srow & 7)) * 8;
    const size_t abase = (size_t)(trow + srow) * K + scc;
    const size_t bbase = (size_t)(tcol + srow) * K + scc;

#define STAGE256(buf, k0)                                                      \
    {                                                                          \
        _Pragma("unroll")                                                      \
        for (int j = 0; j < 4; ++j) {                                          \
            gload_lds16(A + abase + (size_t)j * 64 * K + (k0),                 \
                        &Asm[buf][(j * 512 + t) * 8]);                         \
            gload_lds16(Bw + bbase + (size_t)j * 64 * K + (k0),                \
                        &Bsm[buf][(j * 512 + t) * 8]);                         \
        }                                                                      \
    }
#define LOADA(dst, qr, kk)                                                     \
    _Pragma("unroll") for (int m = 0; m < 4; ++m) {                            \
        const int row = wm * 128 + (qr) * 64 + m * 16 + lq;                    \
        dst[m] = *(const s16x8*)&Asm[cur][row * 64 +                           \
                        ((((kk) * 4 + lg) ^ (row & 7)) * 8)];                  \
    }
#define LOADB(dst, qc, kk)                                                     \
    _Pragma("unroll") for (int n = 0; n < 2; ++n) {                            \
        const int row = wn * 64 + (qc) * 32 + n * 16 + lq;                     \
        dst[n] = *(const s16x8*)&Bsm[cur][row * 64 +                           \
                        ((((kk) * 4 + lg) ^ (row & 7)) * 8)];                  \
    }
#define MFMA8(qr, qc, aset, bset)                                              \
    _Pragma("unroll") for (int m = 0; m < 4; ++m)                              \
        _Pragma("unroll") for (int n = 0; n < 2; ++n)                          \
            acc[(qr) * 4 + m][(qc) * 2 + n] =                                  \
                __builtin_amdgcn_mfma_f32_16x16x32_bf16(                       \
                    aset[m], bset[n], acc[(qr) * 4 + m][(qc) * 2 + n], 0,0,0);

    STAGE256(0, 0);
    asm volatile("s_waitcnt vmcnt(0)" ::: "memory");
    __builtin_amdgcn_s_barrier();

    const int NT = K / 64;
    for (int kt = 0; kt < NT; ++kt) {
        const int cur = kt & 1, nxt = cur ^ 1;
        s16x8 a00[4], a10[4], a11[4], a01[4];
        s16x8 b00[2], b10[2], b01[2], b11[2];
        if (kt < NT - 1) STAGE256(nxt, (kt + 1) * 64);
        LOADA(a00, 0, 0); LOADB(b00, 0, 0); LOADB(b10, 1, 0);
        LOADA(a10, 1, 0);                       MFMA8(0, 0, a00, b00);
        LOADA(a11, 1, 1); LOADB(b01, 0, 1);     MFMA8(0, 1, a00, b10);
        LOADB(b11, 1, 1);                       MFMA8(1, 1, a10, b10);
        LOADA(a01, 0, 1);                       MFMA8(1, 0, a10, b00);
                                                MFMA8(1, 0, a11, b01);
                                                MFMA8(1, 1, a11, b11);
                                                MFMA8(0, 1, a01, b11);
                                                MFMA8(0, 0, a01, b01);
        asm volatile("s_waitcnt vmcnt(0)" ::: "memory");
        __builtin_amdgcn_s_barrier();
    }

#pragma unroll
    for (int mt = 0; mt < 8; ++mt)
#pragma unroll
        for (int nt = 0; nt < 4; ++nt)
#pragma unroll
            for (int r = 0; r < 4; ++r) {
                int row = trow + wm * 128 + mt * 16 + lg * 4 + r;
                int col = tcol + wn * 64 + nt * 16 + lq;
                Cout[(size_t)row * Nout + col] = f2bfc(acc[mt][nt][r]);
            }
#undef STAGE256
#undef LOADA
#undef LOADB
#undef MFMA8
}

// ---------------- fused flash attention (QBLK=256, KVBLK=64 -- r13 exact) ----------------
// KVBLK=128 permanently rejected: twice measured (r10, r14) at ~96us with 159MB FETCH
// (zero L2 reuse), vs KVBLK=64's ~37us / ~25MB.
__global__ __launch_bounds__(512, 4) void attn_fwd(const ushort* __restrict__ qk,
                                                   const ushort* __restrict__ vt,
                                                   ushort* __restrict__ attn_out) {
    __shared__ ushort Klds[64 * 64];
    __shared__ ushort Vlds[64 * 64];

    const int t = threadIdx.x, l = t & 63, w = t >> 6;
    const int lq = l & 15, lg = l >> 4;

    const int serial = blockIdx.x + 4 * blockIdx.y;
    const int logical = (serial & 7) * 64 + (serial >> 3);
    const int qt = logical & 3;
    const int bh = logical >> 2;
    const int b = bh >> 4, h = bh & 15;

    const int qbase = qt * 256 + w * 32 + lq;
    const size_t qoff0 = (size_t)(b * N_ + qbase) * 2048 + h * 64;
    const size_t qoff1 = qoff0 + (size_t)16 * 2048;
    const s16x8 qa0 = *(const s16x8*)&qk[qoff0 + lg * 8];
    const s16x8 qa1 = *(const s16x8*)&qk[qoff0 + 32 + lg * 8];
    const s16x8 qb0 = *(const s16x8*)&qk[qoff1 + lg * 8];
    const s16x8 qb1 = *(const s16x8*)&qk[qoff1 + 32 + lg * 8];

    float lr0 = 0.f, lr1 = 0.f;
    f32x4 o0[4] = {}, o1[4] = {};

    const int srow0 = t >> 3;
    const int sc8 = ((t & 7) ^ (srow0 & 7)) * 8;
    const size_t kgbase = (size_t)(b * N_ + srow0) * 2048 + 1024 + h * 64 + sc8;

    const ushort* vptr[4];
#pragma unroll
    for (int j = 0; j < 4; ++j) {
        const int d = 8 * w + 2 * j + (l >> 5);
        const int c = ((l & 31) >> 2) ^ (d & 7);
        const int s = c * 8 + (l & 3) * 2;
        const int key = (s >> 5) * 32 + ((s >> 2) & 1) * 16 + ((s >> 3) & 3) * 4 + (s & 3);
        vptr[j] = vt + (size_t)(h * 64 + d) * (B_ * N_) + b * N_ + key;
    }

    for (int kt = 0; kt < N_ / 64; ++kt) {
        gload_lds16(qk + kgbase + (size_t)kt * 64 * 2048, &Klds[w * 512]);
#pragma unroll
        for (int j = 0; j < 4; ++j)
            gload_lds4(vptr[j] + kt * 64, &Vlds[w * 512 + j * 128]);
        __syncthreads();

        f32x4 s0[4], s1[4];
#pragma unroll
        for (int g = 0; g < 4; ++g) {
            int key = g * 16 + lq;
            const s16x8 kf0 = *(const s16x8*)&Klds[key * 64 + ((lg ^ (key & 7)) * 8)];
            const s16x8 kf1 = *(const s16x8*)&Klds[key * 64 + (((4 + lg) ^ (key & 7)) * 8)];
            f32x4 z0 = {}, z1 = {};
            z0    = __builtin_amdgcn_mfma_f32_16x16x32_bf16(kf0, qa0, z0, 0, 0, 0);
            s0[g] = __builtin_amdgcn_mfma_f32_16x16x32_bf16(kf1, qa1, z0, 0, 0, 0);
            z1    = __builtin_amdgcn_mfma_f32_16x16x32_bf16(kf0, qb0, z1, 0, 0, 0);
            s1[g] = __builtin_amdgcn_mfma_f32_16x16x32_bf16(kf1, qb1, z1, 0, 0, 0);
        }

#pragma unroll
        for (int kb = 0; kb < 2; ++kb) {
            s16x8 pf0, pf1;
#pragma unroll
            for (int i = 0; i < 4; ++i) {
                float a0 = __builtin_amdgcn_exp2f(s0[2 * kb][i]);
                float a1 = __builtin_amdgcn_exp2f(s0[2 * kb + 1][i]);
                float b0 = __builtin_amdgcn_exp2f(s1[2 * kb][i]);
                float b1 = __builtin_amdgcn_exp2f(s1[2 * kb + 1][i]);
                lr0 += a0 + a1;
                lr1 += b0 + b1;
                pf0[i] = (short)f2bfc(a0); pf0[4 + i] = (short)f2bfc(a1);
                pf1[i] = (short)f2bfc(b0); pf1[4 + i] = (short)f2bfc(b1);
            }
#pragma unroll
            for (int ds = 0; ds < 4; ++ds) {
                const s16x8 vf = *(const s16x8*)
                    &Vlds[(ds * 16 + lq) * 64 + (((kb * 4 + lg) ^ (lq & 7)) * 8)];
                o0[ds] = __builtin_amdgcn_mfma_f32_16x16x32_bf16(pf0, vf, o0[ds], 0, 0, 0);
                o1[ds] = __builtin_amdgcn_mfma_f32_16x16x32_bf16(pf1, vf, o1[ds], 0, 0, 0);
            }
        }
        __syncthreads();
    }

    lr0 += __shfl_xor(lr0, 16); lr0 += __shfl_xor(lr0, 32);
    lr1 += __shfl_xor(lr1, 16); lr1 += __shfl_xor(lr1, 32);

#pragma unroll
    for (int r = 0; r < 4; ++r) {
        float rl0 = 1.f / __shfl(lr0, lg * 4 + r);
        float rl1 = 1.f / __shfl(lr1, lg * 4 + r);
        int orow = qt * 256 + w * 32 + lg * 4 + r;
        size_t base0 = (size_t)(b * N_ + orow) * C_ + h * 64 + lq;
        size_t base1 = base0 + (size_t)16 * C_;
#pragma unroll
        for (int ds = 0; ds < 4; ++ds) {
            attn_out[base0 + ds * 16] = f2bfc(o0[ds][r] * rl0);
            attn_out[base1 + ds * 16] = f2bfc(o1[ds][r] * rl1);
        }
    }
}

extern "C" void kernel_launch(void* const* d_in, const int* in_sizes, int n_in,
                              void* d_out, int out_size, void* d_ws, size_t ws_size,
                              hipStream_t stream) {
    const float* x      = (const float*)d_in[0];
    const float* qkv_w  = (const float*)d_in[1];
    const float* proj_w = (const float*)d_in[2];
    const float* proj_b = (const float*)d_in[3];
    float* out = (float*)d_out;

    ushort* ws    = (ushort*)d_ws;
    ushort* xb    = ws;                                   //  8192*1024
    ushort* wqkv  = xb + (size_t)8192 * 1024;             //  3072*1024
    ushort* wproj = wqkv + (size_t)3072 * 1024;           //  1024*1024
    ushort* qkb   = wproj + (size_t)1024 * 1024;          //  8192*2048
    ushort* vtb   = qkb + (size_t)8192 * 2048;            //  1024*8192
    ushort* attn  = vtb + (size_t)1024 * 8192;            //  8192*1024

    cvt_all<<<12288, 256, 0, stream>>>(x, qkv_w, proj_w, xb, wqkv, wproj);

    // Q,K: [token][2048] via 256^2 dbuf v3
    gemm_bt256<<<dim3(8, 32), 512, 0, stream>>>(xb, wqkv, qkb, 8192, 2048, 1024);
    // V^T: [c][token]
    gemm_bt<1><<<dim3(64, 8), 256, 0, stream>>>(wqkv + (size_t)2048 * 1024, xb, (void*)vtb,
                                                nullptr, 1024, 8192, 1024);

    attn_fwd<<<dim3(4, 128), 512, 0, stream>>>(qkb, vtb, attn);

    gemm_bt<0><<<dim3(8, 64), 256, 0, stream>>>(attn, wproj, (void*)out, proj_b, 8192, 1024, 1024);
}